// Round 8
// baseline (3387.334 us; speedup 1.0000x reference)
//
#include <hip/hip_runtime.h>
#include <stdint.h>

// Problem dims
#define T_STEPS 512
#define BATCH   64
#define DIN     256
#define HID     512
#define KTOT    768   // DIN + HID
#define NTEAMS  4
#define TB      16
#define KK_X    8     // k-tiles (K=32) covering x part
#define KK_H    16    // k-tiles covering h part
#define KK_ALL  24

// bounded spin: convert any protocol failure into a terminating wrong answer
#define POLL_BOUND (1 << 18)

typedef __bf16 v8bf __attribute__((ext_vector_type(8)));
typedef float  v4f  __attribute__((ext_vector_type(4)));
typedef unsigned int v4u __attribute__((ext_vector_type(4)));
typedef unsigned int v2u __attribute__((ext_vector_type(2)));

// workspace layout (bytes)
#define FLAGS_OFF 0                       // [4 team][128 wave-flag] u32 = 2048
#define HBUF_OFF  4096                    // [4 team][2 parity][16][512] u16 = 131072
#define WPK_OFF   (HBUF_OFF + 131072)     // [128 wv][24 kk][64 lane][8] u16 = 3145728
#define XPK_OFF   (WPK_OFF + 3145728)     // [512 t][4 team][8 kk][64 lane][8] u16 = 16777216

// ---- single-instruction asm memory helpers (device scope = sc1 / IC point) ----
#define LOADX4_DEV(d, a, IMM) \
  asm volatile("global_load_dwordx4 %0, %1, off offset:" IMM " sc1" \
               : "=v"(d) : "v"(a) : "memory")
#define LOADX2_DEV_W(d, a) \
  asm volatile("global_load_dwordx2 %0, %1, off sc1\n\ts_waitcnt vmcnt(0)" \
               : "=v"(d) : "v"(a) : "memory")
#define ST2_DEV(a, v) \
  asm volatile("global_store_dwordx2 %0, %1, off sc1" :: "v"(a), "v"(v) : "memory")
#define ST_DW_DEV(a, v) \
  asm volatile("global_store_dword %0, %1, off sc1" :: "v"(a), "v"(v) : "memory")
#define LOADX4(d, a) \
  asm volatile("global_load_dwordx4 %0, %1, off" : "=v"(d) : "v"(a) : "memory")
#define DRAIN_VM() asm volatile("s_waitcnt vmcnt(0)" ::: "memory")

static __device__ __forceinline__ unsigned short f2bf(float x) {
  union { float f; uint32_t u; } v; v.f = x;
  uint32_t r = (v.u + 0x7fffu + ((v.u >> 16) & 1u)) >> 16;
  return (unsigned short)r;
}

static __device__ __forceinline__ float sigm(float x) {
  float e = __builtin_amdgcn_exp2f(-1.44269504f * x);
  return __builtin_amdgcn_rcpf(1.0f + e);
}
static __device__ __forceinline__ float tanh_(float x) {
  float e = __builtin_amdgcn_exp2f(2.88539008f * x);    // exp(2x)
  return 1.0f - 2.0f * __builtin_amdgcn_rcpf(e + 1.0f); // inf-safe -> +/-1
}

// ---- Prologue: pack weights into MFMA A-fragment order (bf16) ---- (R5-proven)
__global__ void pack_w(const float* __restrict__ Wf, const float* __restrict__ Wi,
                       const float* __restrict__ Wg, const float* __restrict__ Wo,
                       unsigned short* __restrict__ wpk) {
  int n = blockIdx.x * 256 + threadIdx.x;           // 128*24*64 = 196608 chunks
  int l  = n & 63;
  int kk = (n >> 6) % KK_ALL;
  int wv = (n >> 6) / KK_ALL;                       // cu*4 + w, 0..127
  int row  = l & 15;
  int gate = row & 3;
  int unit = (wv >> 2) * 16 + (wv & 3) * 4 + (row >> 2);
  int col  = kk * 32 + (l >> 4) * 8;
  const float* W = (gate == 0) ? Wf : (gate == 1) ? Wi : (gate == 2) ? Wg : Wo;
  const float* src = W + (size_t)unit * KTOT + col;
  unsigned short* dst = wpk + (size_t)n * 8;
#pragma unroll
  for (int e = 0; e < 8; e++) dst[e] = f2bf(src[e]);
}

// ---- Prologue: pack x into MFMA B-fragment order (bf16) ---- (R5-proven)
__global__ void pack_x(const float* __restrict__ X, unsigned short* __restrict__ xpk) {
  int n = blockIdx.x * 256 + threadIdx.x;           // 512*4*8*64 = 1048576 chunks
  int l    = n & 63;
  int kk   = (n >> 6) & 7;
  int team = (n >> 9) & 3;
  int t    = n >> 11;
  int b    = team * TB + (l & 15);
  int col  = kk * 32 + (l >> 4) * 8;
  const float* src = X + ((size_t)(t * BATCH + b)) * DIN + col;
  unsigned short* dst = xpk + (size_t)n * 8;
#pragma unroll
  for (int e = 0; e < 8; e++) dst[e] = f2bf(src[e]);
}

// ---- Persistent recurrent kernel ----
// grid 256 x block 256. team = blk&7 (>=NTEAMS exits), cu = blk>>3 (0..31).
// Per-WAVE flags (no intra-block publish barrier), all-waves polling (no
// post-poll barrier), double-buffered LDS (one barrier/step). Device-scope
// sc1 protocol, R5-proven data path. Correct under ANY placement.
__global__ void __launch_bounds__(256, 1)
lstm_rec(const float* __restrict__ bf_, const float* __restrict__ bi_,
         const float* __restrict__ bg_, const float* __restrict__ bo_,
         const unsigned short* __restrict__ wpk, const unsigned short* __restrict__ xpk,
         float* __restrict__ out, unsigned int* flags, unsigned short* hbuf) {
  int blk  = blockIdx.x;
  int team = blk & 7;
  if (team >= NTEAMS) return;
  int cu  = blk >> 3;              // 0..31
  int tid = threadIdx.x;
  int w   = tid >> 6, l = tid & 63;
  int brow = l & 15;               // team-local batch row (B-frag col / C col)
  int ul   = l >> 4;               // 0..3
  int u    = cu * 16 + w * 4 + ul; // hidden unit owned by this lane
  int bglob = team * TB + brow;

  __shared__ v4u hls[2048];        // 2 x 16 KB swizzled h image (double buffer)

  // stationary weight fragments via asm loads (parked in AGPRs, R5/R7-proven)
  v4u wfu[KK_ALL];
  {
    const char* wp = (const char*)(wpk + ((size_t)(cu * 4 + w)) * (KK_ALL * 512) + l * 8);
#pragma unroll
    for (int kk = 0; kk < KK_ALL; kk++) LOADX4(wfu[kk], wp + (size_t)kk * 1024);
    DRAIN_VM();
  }
  float b0 = bf_[u], b1 = bi_[u], b2 = bg_[u], b3 = bo_[u];
  float c = 0.0f, hval = 0.0f;

  // h-slab pointers (parity double buffer), linear [brow][unit] u16 rows of 1024B
  char* slab0 = (char*)(hbuf + (size_t)team * 2 * (TB * HID));
  char* slab1 = slab0 + TB * HID * 2;

  unsigned int* ftm = flags + (size_t)team * 128;     // this team's 128 wave flags
  unsigned int* myflag = ftm + (size_t)(cu * 4 + w);  // this wave's flag
  const unsigned int* fp = ftm + 2 * l;               // poll: 2 flags per lane

  float* outb = out + (size_t)bglob * HID + u;

  for (int t = 0; t < T_STEPS; t++) {
    // x-part B-frags: plain cached loads (xpk read-only, L2-resident)
    v8bf xf[KK_X];
    {
      const v8bf* xp = (const v8bf*)(xpk + ((size_t)(t * NTEAMS + team)) * (KK_X * 512) + l * 8);
#pragma unroll
      for (int kk = 0; kk < KK_X; kk++) xf[kk] = xp[kk * 64];
    }

    // per-wave poll of all 128 wave-flags (one dwordx2 per lane)
    if (t > 0) {
      unsigned int tg = (unsigned)t;
      int guard = 0;
      while (true) {
        v2u fv;
        LOADX2_DEV_W(fv, fp);
        __builtin_amdgcn_sched_barrier(0);   // rule #18
        if (__all(fv.x >= tg && fv.y >= tg)) break;
        if (++guard > POLL_BOUND) break;     // degrade, never hang
      }
    }

    // stage this wave's quarter of the h image (4KB): rows w*4..w*4+3
    v4u s0, s1, s2, s3;
    {
      const char* sb = ((t & 1) ? slab1 : slab0) + w * 4096 + l * 16;
      LOADX4_DEV(s0, sb, "0");
      LOADX4_DEV(s1, sb, "1024");
      LOADX4_DEV(s2, sb, "2048");
      LOADX4_DEV(s3, sb, "3072");
    }

    // x-part MFMAs overlap the stage-load latency
    v4f acc[4];
    acc[0] = (v4f){b0, b1, b2, b3};
    acc[1] = (v4f){0.f, 0.f, 0.f, 0.f};
    acc[2] = (v4f){0.f, 0.f, 0.f, 0.f};
    acc[3] = (v4f){0.f, 0.f, 0.f, 0.f};
#pragma unroll
    for (int kk = 0; kk < KK_X; kk++)
      acc[kk & 3] = __builtin_amdgcn_mfma_f32_16x16x32_bf16(
          __builtin_bit_cast(v8bf, wfu[kk]), xf[kk], acc[kk & 3], 0, 0, 0);

    DRAIN_VM();                          // stage loads complete
    __builtin_amdgcn_sched_barrier(0);   // rule #18

    // LDS writes with XOR swizzle into parity half: byte ^= (row&7)<<4
    char* hl = (char*)hls + (t & 1) * 16384;
    {
      int r = w * 4;
      *(v4u*)(hl + (((r + 0) * 1024 + l * 16) ^ (((r + 0) & 7) << 4))) = s0;
      *(v4u*)(hl + (((r + 1) * 1024 + l * 16) ^ (((r + 1) & 7) << 4))) = s1;
      *(v4u*)(hl + (((r + 2) * 1024 + l * 16) ^ (((r + 2) & 7) << 4))) = s2;
      *(v4u*)(hl + (((r + 3) * 1024 + l * 16) ^ (((r + 3) & 7) << 4))) = s3;
    }
    __syncthreads();   // the ONE barrier per step (dbuf covers cross-step hazard)

    // h-part MFMAs from LDS (swizzled reads, R5-proven layout)
#pragma unroll
    for (int kk = 0; kk < KK_H; kk++) {
      int off = (brow * 1024 + kk * 64 + ul * 16) ^ ((brow & 7) << 4);
      v8bf hf = *(const v8bf*)(hl + off);
      acc[kk & 3] = __builtin_amdgcn_mfma_f32_16x16x32_bf16(
          __builtin_bit_cast(v8bf, wfu[KK_X + kk]), hf, acc[kk & 3], 0, 0, 0);
    }
    v4f g4 = (acc[0] + acc[1]) + (acc[2] + acc[3]);

    // gates are lane-local: f,i,g,o for (unit u, batch bglob)
    float fg = sigm(g4[0]);
    float ig = sigm(g4[1]);
    float gg = tanh_(g4[2]);
    float og = sigm(g4[3]);
    c    = fg * c + ig * gg;
    hval = og * tanh_(c);

    if (t < T_STEPS - 1) {
      // publish h_{t+1}: pack this wave's 4 units per brow into 8B, 16 lanes
      float h0 = __shfl(hval, brow);
      float h1 = __shfl(hval, brow + 16);
      float h2 = __shfl(hval, brow + 32);
      float h3 = __shfl(hval, brow + 48);
      if (l < 16) {
        v2u pk;
        pk.x = (unsigned)f2bf(h0) | ((unsigned)f2bf(h1) << 16);
        pk.y = (unsigned)f2bf(h2) | ((unsigned)f2bf(h3) << 16);
        char* pd = (((t + 1) & 1) ? slab1 : slab0) + brow * 1024 + cu * 32 + w * 8;
        ST2_DEV(pd, pk);
      }
      DRAIN_VM();                        // this wave's publish acked at IC
      if (l == 0) ST_DW_DEV(myflag, (unsigned)(t + 1));  // per-WAVE flag
    }

    // outputs[t][b][u] — plain cached store, off the critical path
    outb[(size_t)t * (BATCH * HID)] = hval;
  }

  // final hx, cx
  float* hx = out + (size_t)T_STEPS * BATCH * HID;
  hx[(size_t)bglob * HID + u] = hval;
  float* cx = hx + BATCH * HID;
  cx[(size_t)bglob * HID + u] = c;
}

extern "C" void kernel_launch(void* const* d_in, const int* in_sizes, int n_in,
                              void* d_out, int out_size, void* d_ws, size_t ws_size,
                              hipStream_t stream) {
  const float* X  = (const float*)d_in[0];
  const float* Wf = (const float*)d_in[1];
  const float* bf = (const float*)d_in[2];
  const float* Wi = (const float*)d_in[3];
  const float* bi = (const float*)d_in[4];
  const float* Wg = (const float*)d_in[5];
  const float* bg = (const float*)d_in[6];
  const float* Wo = (const float*)d_in[7];
  const float* bo = (const float*)d_in[8];
  float* out = (float*)d_out;
  char* ws = (char*)d_ws;

  unsigned int*   flags = (unsigned int*)(ws + FLAGS_OFF);
  unsigned short* hbuf  = (unsigned short*)(ws + HBUF_OFF);
  unsigned short* wpk   = (unsigned short*)(ws + WPK_OFF);
  unsigned short* xpk   = (unsigned short*)(ws + XPK_OFF);

  // zero flags + h double-buffers every call (graph-replay determinism)
  hipMemsetAsync(ws, 0, WPK_OFF, stream);
  pack_w<<<768, 256, 0, stream>>>(Wf, Wi, Wg, Wo, wpk);
  pack_x<<<4096, 256, 0, stream>>>(X, xpk);
  lstm_rec<<<256, 256, 0, stream>>>(bf, bi, bg, bo, wpk, xpk, out, flags, hbuf);
}

// Round 9
// 1631.076 us; speedup vs baseline: 2.0767x; 2.0767x over previous
//
#include <hip/hip_runtime.h>
#include <stdint.h>

// Problem dims
#define T_STEPS 512
#define BATCH   64
#define DIN     256
#define HID     512
#define KTOT    768   // DIN + HID
#define NTEAMS  4
#define TB      16
#define KK_X    8     // k-tiles (K=32) covering x part
#define KK_H    16    // k-tiles covering h part
#define KK_ALL  24

// bounded spins: convert any protocol failure into a terminating wrong answer
#define POLL_BOUND (1 << 18)
#define DET_BOUND  (1 << 20)

typedef __bf16 v8bf __attribute__((ext_vector_type(8)));
typedef float  v4f  __attribute__((ext_vector_type(4)));
typedef unsigned int v4u __attribute__((ext_vector_type(4)));
typedef unsigned int v2u __attribute__((ext_vector_type(2)));

// ---------------- workspace layouts ----------------
// MONO layout (needs ~51MB):
#define FLAGS_OFF 0                        // [4 team][32 cu] u32 @ 64B stride = 8192
#define XCDB_OFF  8192                     // [4 team][32 cu] u32
#define XCNT_OFF  8704                     // [4 team] u32 @ 64B stride
#define WPK_OFF   16384                    // 3145728
#define XPK_OFF   (WPK_OFF + 3145728)      // 16777216
#define HBUF_OFF  (XPK_OFF + 16777216)     // [512 t][4 team][16][512] u16 = 33554432
#define WS_NEED   ((size_t)HBUF_OFF + 33554432u)
// R5 layout (fallback, proven):
#define FLAGS5_OFF 0                       // 8192
#define HBUF5_OFF  8192                    // [4 team][2 parity][16][512] u16 = 131072
#define WPK5_OFF   (HBUF5_OFF + 131072)
#define XPK5_OFF   (WPK5_OFF + 3145728)

// ---- single-instruction asm memory helpers ----
#define LOADX4_DEV(d, a, IMM) \
  asm volatile("global_load_dwordx4 %0, %1, off offset:" IMM " sc1" \
               : "=v"(d) : "v"(a) : "memory")
#define LOADX4_PLAIN(d, a, IMM) \
  asm volatile("global_load_dwordx4 %0, %1, off offset:" IMM \
               : "=v"(d) : "v"(a) : "memory")
#define ST2_DEV(a, v) \
  asm volatile("global_store_dwordx2 %0, %1, off sc1" :: "v"(a), "v"(v) : "memory")
#define ST2_PLAIN(a, v) \
  asm volatile("global_store_dwordx2 %0, %1, off" :: "v"(a), "v"(v) : "memory")
#define ST_DW_DEV(a, v) \
  asm volatile("global_store_dword %0, %1, off sc1" :: "v"(a), "v"(v) : "memory")
#define ST_DW_SYS(a, v) \
  asm volatile("global_store_dword %0, %1, off sc0 sc1" :: "v"(a), "v"(v) : "memory")
#define LOADX4(d, a) \
  asm volatile("global_load_dwordx4 %0, %1, off" : "=v"(d) : "v"(a) : "memory")
#define LOAD_DW_NB(d, a) \
  asm volatile("global_load_dword %0, %1, off sc1" : "=v"(d) : "v"(a) : "memory")
#define WAIT1() asm volatile("s_waitcnt vmcnt(1)" ::: "memory")
#define DRAIN_VM() asm volatile("s_waitcnt vmcnt(0)" ::: "memory")

static __device__ __forceinline__ unsigned int ld_flag_dev(const unsigned int* p) {
  unsigned int v;
  asm volatile("global_load_dword %0, %1, off sc1\n\ts_waitcnt vmcnt(0)"
               : "=v"(v) : "v"(p) : "memory");
  return v;
}
static __device__ __forceinline__ unsigned int ld_dword_sys(const unsigned int* p) {
  unsigned int v;
  asm volatile("global_load_dword %0, %1, off sc0 sc1\n\ts_waitcnt vmcnt(0)"
               : "=v"(v) : "v"(p) : "memory");
  return v;
}

static __device__ __forceinline__ unsigned short f2bf(float x) {
  union { float f; uint32_t u; } v; v.f = x;
  uint32_t r = (v.u + 0x7fffu + ((v.u >> 16) & 1u)) >> 16;
  return (unsigned short)r;
}
static __device__ __forceinline__ float sigm(float x) {
  float e = __builtin_amdgcn_exp2f(-1.44269504f * x);
  return __builtin_amdgcn_rcpf(1.0f + e);
}
static __device__ __forceinline__ float tanh_(float x) {
  float e = __builtin_amdgcn_exp2f(2.88539008f * x);
  return 1.0f - 2.0f * __builtin_amdgcn_rcpf(e + 1.0f);
}

// ---- Prologue: pack weights into MFMA A-fragment order (bf16) ---- (proven)
__global__ void pack_w(const float* __restrict__ Wf, const float* __restrict__ Wi,
                       const float* __restrict__ Wg, const float* __restrict__ Wo,
                       unsigned short* __restrict__ wpk) {
  int n = blockIdx.x * 256 + threadIdx.x;
  int l  = n & 63;
  int kk = (n >> 6) % KK_ALL;
  int wv = (n >> 6) / KK_ALL;
  int row  = l & 15;
  int gate = row & 3;
  int unit = (wv >> 2) * 16 + (wv & 3) * 4 + (row >> 2);
  int col  = kk * 32 + (l >> 4) * 8;
  const float* W = (gate == 0) ? Wf : (gate == 1) ? Wi : (gate == 2) ? Wg : Wo;
  const float* src = W + (size_t)unit * KTOT + col;
  unsigned short* dst = wpk + (size_t)n * 8;
#pragma unroll
  for (int e = 0; e < 8; e++) dst[e] = f2bf(src[e]);
}

// ---- Prologue: pack x into MFMA B-fragment order (bf16) ---- (proven)
__global__ void pack_x(const float* __restrict__ X, unsigned short* __restrict__ xpk) {
  int n = blockIdx.x * 256 + threadIdx.x;
  int l    = n & 63;
  int kk   = (n >> 6) & 7;
  int team = (n >> 9) & 3;
  int t    = n >> 11;
  int b    = team * TB + (l & 15);
  int col  = kk * 32 + (l >> 4) * 8;
  const float* src = X + ((size_t)(t * BATCH + b)) * DIN + col;
  unsigned short* dst = xpk + (size_t)n * 8;
#pragma unroll
  for (int e = 0; e < 8; e++) dst[e] = f2bf(src[e]);
}

// =====================================================================
// MONO kernel: monotonic per-step h slabs (no address reuse within a
// launch -> consumer L1 first-touch; replay staleness value-identical by
// determinism). Payload scope: plain (local-L2) if team XCD-uniform,
// sc1 (IC) otherwise. Flags always sc1 (R5-proven architecture:
// 32 flags/team, 64B stride, wave0 polls, tid0 writes).
// =====================================================================
__global__ void __launch_bounds__(256, 1)
lstm_mono(const float* __restrict__ bf_, const float* __restrict__ bi_,
          const float* __restrict__ bg_, const float* __restrict__ bo_,
          const unsigned short* __restrict__ wpk, const unsigned short* __restrict__ xpk,
          float* __restrict__ out, unsigned int* flags, unsigned int* xcdb,
          unsigned int* xcnt, unsigned short* hbuf) {
  int blk  = blockIdx.x;
  int team = blk & 7;
  if (team >= NTEAMS) return;
  int cu  = blk >> 3;
  int tid = threadIdx.x;
  int w   = tid >> 6, l = tid & 63;
  int brow = l & 15;
  int ul   = l >> 4;
  int u    = cu * 16 + w * 4 + ul;
  int bglob = team * TB + brow;

  __shared__ v4u hls[2048];        // 2 x 16 KB swizzled h image (double buffer)
  __shared__ int mode_sh;

  // one-time: is this team XCD-uniform? (R4-proven machinery, bounded)
  {
    unsigned int* xb = xcdb + team * 32;
    unsigned int* xc = xcnt + team * 16;
    if (w == 0) {
      if (l == 0) {
        unsigned int myx;
        asm volatile("s_getreg_b32 %0, hwreg(HW_REG_XCC_ID)" : "=s"(myx));
        ST_DW_SYS(xb + cu, myx + 1u);   // +1 so timeout-zeros read as distinct
        DRAIN_VM();
        __hip_atomic_fetch_add(xc, 1u, __ATOMIC_RELEASE, __HIP_MEMORY_SCOPE_AGENT);
        int guard = 0;
        while (__hip_atomic_load(xc, __ATOMIC_ACQUIRE, __HIP_MEMORY_SCOPE_AGENT) < 32u) {
          if (++guard > DET_BOUND) break;
        }
      }
      unsigned int xv = ld_dword_sys(xb + (l & 31));
      int ok = (__all(xv == __shfl(xv, 0)) && __shfl(xv, 0) != 0u) ? 1 : 0;
      if (l == 0) mode_sh = ok;
    }
    __syncthreads();
  }
  const int fastsc = mode_sh;

  // stationary weight fragments (forced resident via asm loads)
  v4u wfu[KK_ALL];
  {
    const char* wp = (const char*)(wpk + ((size_t)(cu * 4 + w)) * (KK_ALL * 512) + l * 8);
#pragma unroll
    for (int kk = 0; kk < KK_ALL; kk++) LOADX4(wfu[kk], wp + (size_t)kk * 1024);
    DRAIN_VM();
  }
  float b0 = bf_[u], b1 = bi_[u], b2 = bg_[u], b3 = bo_[u];
  float c = 0.0f, hval = 0.0f;

  unsigned int* ftm = flags + (size_t)team * 32 * 16;  // 32 flags, 64B stride
  unsigned int* myflag = ftm + (size_t)cu * 16;

  float* outb = out + (size_t)bglob * HID + u;

  for (int t = 0; t < T_STEPS; t++) {
    // x-part B-frags (plain cached; xpk read-only)
    v8bf xf[KK_X];
    {
      const v8bf* xp = (const v8bf*)(xpk + ((size_t)(t * NTEAMS + team)) * (KK_X * 512) + l * 8);
#pragma unroll
      for (int kk = 0; kk < KK_X; kk++) xf[kk] = xp[kk * 64];
    }

    // x-part MFMAs
    v4f acc[4];
    acc[0] = (v4f){b0, b1, b2, b3};
    acc[1] = (v4f){0.f, 0.f, 0.f, 0.f};
    acc[2] = (v4f){0.f, 0.f, 0.f, 0.f};
    acc[3] = (v4f){0.f, 0.f, 0.f, 0.f};
#pragma unroll
    for (int kk = 0; kk < KK_X; kk++)
      acc[kk & 3] = __builtin_amdgcn_mfma_f32_16x16x32_bf16(
          __builtin_bit_cast(v8bf, wfu[kk]), xf[kk], acc[kk & 3], 0, 0, 0);

    if (t > 0) {
      // wave0: pipelined 2-deep poll of 32 sc1 flags (half-RT cadence)
      if (w == 0) {
        const unsigned int* pp = ftm + (size_t)(l & 31) * 16;
        unsigned int tg = (unsigned)t;
        unsigned int fa, fb;
        LOAD_DW_NB(fa, pp);
        int guard = 0;
        while (true) {
          LOAD_DW_NB(fb, pp);
          WAIT1();
          __builtin_amdgcn_sched_barrier(0);
          if (__all(fa >= tg)) break;
          LOAD_DW_NB(fa, pp);
          WAIT1();
          __builtin_amdgcn_sched_barrier(0);
          if (__all(fb >= tg)) break;
          if ((guard += 2) > POLL_BOUND) break;   // degrade, never hang
        }
      }
      __syncthreads();

      // stage this wave's quarter of slab[t] (4KB): rows w*4..w*4+3
      const char* slab_t = (const char*)(hbuf + ((size_t)t * NTEAMS + team) * (TB * HID));
      const char* sb = slab_t + w * 4096 + l * 16;
      v4u s0, s1, s2, s3;
      if (fastsc) {
        LOADX4_PLAIN(s0, sb, "0");
        LOADX4_PLAIN(s1, sb, "1024");
        LOADX4_PLAIN(s2, sb, "2048");
        LOADX4_PLAIN(s3, sb, "3072");
      } else {
        LOADX4_DEV(s0, sb, "0");
        LOADX4_DEV(s1, sb, "1024");
        LOADX4_DEV(s2, sb, "2048");
        LOADX4_DEV(s3, sb, "3072");
      }
      DRAIN_VM();
      __builtin_amdgcn_sched_barrier(0);   // rule #18

      // LDS writes with XOR swizzle into parity half
      char* hl = (char*)hls + (t & 1) * 16384;
      {
        int r = w * 4;
        *(v4u*)(hl + (((r + 0) * 1024 + l * 16) ^ (((r + 0) & 7) << 4))) = s0;
        *(v4u*)(hl + (((r + 1) * 1024 + l * 16) ^ (((r + 1) & 7) << 4))) = s1;
        *(v4u*)(hl + (((r + 2) * 1024 + l * 16) ^ (((r + 2) & 7) << 4))) = s2;
        *(v4u*)(hl + (((r + 3) * 1024 + l * 16) ^ (((r + 3) & 7) << 4))) = s3;
      }
      __syncthreads();   // barrier B

      // h-part MFMAs from LDS (proven swizzled layout)
#pragma unroll
      for (int kk = 0; kk < KK_H; kk++) {
        int off = (brow * 1024 + kk * 64 + ul * 16) ^ ((brow & 7) << 4);
        v8bf hf = *(const v8bf*)(hl + off);
        acc[kk & 3] = __builtin_amdgcn_mfma_f32_16x16x32_bf16(
            __builtin_bit_cast(v8bf, wfu[KK_X + kk]), hf, acc[kk & 3], 0, 0, 0);
      }
    }
    // t == 0: h = 0 -> x-part + bias only

    v4f g4 = (acc[0] + acc[1]) + (acc[2] + acc[3]);
    float fg = sigm(g4[0]);
    float ig = sigm(g4[1]);
    float gg = tanh_(g4[2]);
    float og = sigm(g4[3]);
    c    = fg * c + ig * gg;
    hval = og * tanh_(c);

    if (t < T_STEPS - 1) {
      // publish h_{t+1} into slab[t+1]; scope per detection
      float h0 = __shfl(hval, brow);
      float h1 = __shfl(hval, brow + 16);
      float h2 = __shfl(hval, brow + 32);
      float h3 = __shfl(hval, brow + 48);
      char* slab_n = (char*)(hbuf + ((size_t)(t + 1) * NTEAMS + team) * (TB * HID));
      if (l < 16) {
        v2u pk;
        pk.x = (unsigned)f2bf(h0) | ((unsigned)f2bf(h1) << 16);
        pk.y = (unsigned)f2bf(h2) | ((unsigned)f2bf(h3) << 16);
        char* pd = slab_n + brow * 1024 + cu * 32 + w * 8;
        if (fastsc) { ST2_PLAIN(pd, pk); } else { ST2_DEV(pd, pk); }
      }
      // out store hidden under the publish drain
      outb[(size_t)t * (BATCH * HID)] = hval;
      DRAIN_VM();          // publish (and out) acked at coherence point
      __syncthreads();     // barrier A: all 4 waves drained
      if (tid == 0) ST_DW_DEV(myflag, (unsigned)(t + 1));
    } else {
      outb[(size_t)t * (BATCH * HID)] = hval;
    }
  }

  // final hx, cx
  float* hx = out + (size_t)T_STEPS * BATCH * HID;
  hx[(size_t)bglob * HID + u] = hval;
  float* cx = hx + BATCH * HID;
  cx[(size_t)bglob * HID + u] = c;
}

// =====================================================================
// R5 kernel, verbatim (proven 1348us) — host fallback when ws too small
// =====================================================================
__global__ void __launch_bounds__(256, 1)
lstm_rec_r5(const float* __restrict__ bf_, const float* __restrict__ bi_,
            const float* __restrict__ bg_, const float* __restrict__ bo_,
            const unsigned short* __restrict__ wpk, const unsigned short* __restrict__ xpk,
            float* __restrict__ out, unsigned int* flags, unsigned short* hbuf) {
  int blk  = blockIdx.x;
  int team = blk & 7;
  if (team >= NTEAMS) return;
  int cu  = blk >> 3;
  int tid = threadIdx.x;
  int w   = tid >> 6, l = tid & 63;
  int brow = l & 15;
  int ul   = l >> 4;
  int u    = cu * 16 + w * 4 + ul;
  int bglob = team * TB + brow;

  __shared__ v4u hls[1024];
  char* hl = (char*)hls;

  v4u wfu[KK_ALL];
  {
    const char* wp = (const char*)(wpk + ((size_t)(cu * 4 + w)) * (KK_ALL * 512) + l * 8);
#pragma unroll
    for (int kk = 0; kk < KK_ALL; kk++) LOADX4(wfu[kk], wp + (size_t)kk * 1024);
    DRAIN_VM();
  }
  float b0 = bf_[u], b1 = bi_[u], b2 = bg_[u], b3 = bo_[u];
  float c = 0.0f, hval = 0.0f;

  char* slab0 = (char*)(hbuf + (size_t)team * 2 * (TB * HID));
  char* slab1 = slab0 + TB * HID * 2;
  unsigned int* ftm = flags + (size_t)team * 32 * 16;
  unsigned int* myflag = ftm + (size_t)cu * 16;
  float* outb = out + (size_t)bglob * HID + u;

  for (int t = 0; t < T_STEPS; t++) {
    v8bf xf[KK_X];
    {
      const v8bf* xp = (const v8bf*)(xpk + ((size_t)(t * NTEAMS + team)) * (KK_X * 512) + l * 8);
#pragma unroll
      for (int kk = 0; kk < KK_X; kk++) xf[kk] = xp[kk * 64];
    }
    if (t > 0) {
      if (w == 0) {
        const unsigned int* pp = ftm + (size_t)(l & 31) * 16;
        int guard = 0;
        while (true) {
          unsigned int v = ld_flag_dev(pp);
          if (__all(v >= (unsigned)t)) break;
          if (++guard > POLL_BOUND) break;
        }
      }
      __syncthreads();
    }
    v4u s0, s1, s2, s3;
    {
      const char* sb = ((t & 1) ? slab1 : slab0) + w * 4096 + l * 16;
      LOADX4_DEV(s0, sb, "0");
      LOADX4_DEV(s1, sb, "1024");
      LOADX4_DEV(s2, sb, "2048");
      LOADX4_DEV(s3, sb, "3072");
    }
    v4f acc[4];
    acc[0] = (v4f){b0, b1, b2, b3};
    acc[1] = (v4f){0.f, 0.f, 0.f, 0.f};
    acc[2] = (v4f){0.f, 0.f, 0.f, 0.f};
    acc[3] = (v4f){0.f, 0.f, 0.f, 0.f};
#pragma unroll
    for (int kk = 0; kk < KK_X; kk++)
      acc[kk & 3] = __builtin_amdgcn_mfma_f32_16x16x32_bf16(
          __builtin_bit_cast(v8bf, wfu[kk]), xf[kk], acc[kk & 3], 0, 0, 0);
    DRAIN_VM();
    __builtin_amdgcn_sched_barrier(0);
    {
      int r = w * 4;
      *(v4u*)(hl + (((r + 0) * 1024 + l * 16) ^ (((r + 0) & 7) << 4))) = s0;
      *(v4u*)(hl + (((r + 1) * 1024 + l * 16) ^ (((r + 1) & 7) << 4))) = s1;
      *(v4u*)(hl + (((r + 2) * 1024 + l * 16) ^ (((r + 2) & 7) << 4))) = s2;
      *(v4u*)(hl + (((r + 3) * 1024 + l * 16) ^ (((r + 3) & 7) << 4))) = s3;
    }
    __syncthreads();
#pragma unroll
    for (int kk = 0; kk < KK_H; kk++) {
      int off = (brow * 1024 + kk * 64 + ul * 16) ^ ((brow & 7) << 4);
      v8bf hf = *(const v8bf*)(hl + off);
      acc[kk & 3] = __builtin_amdgcn_mfma_f32_16x16x32_bf16(
          __builtin_bit_cast(v8bf, wfu[KK_X + kk]), hf, acc[kk & 3], 0, 0, 0);
    }
    v4f g4 = (acc[0] + acc[1]) + (acc[2] + acc[3]);
    float fg = sigm(g4[0]);
    float ig = sigm(g4[1]);
    float gg = tanh_(g4[2]);
    float og = sigm(g4[3]);
    c    = fg * c + ig * gg;
    hval = og * tanh_(c);
    if (t < T_STEPS - 1) {
      float h0 = __shfl(hval, brow);
      float h1 = __shfl(hval, brow + 16);
      float h2 = __shfl(hval, brow + 32);
      float h3 = __shfl(hval, brow + 48);
      if (l < 16) {
        v2u pk;
        pk.x = (unsigned)f2bf(h0) | ((unsigned)f2bf(h1) << 16);
        pk.y = (unsigned)f2bf(h2) | ((unsigned)f2bf(h3) << 16);
        char* pd = (((t + 1) & 1) ? slab1 : slab0) + brow * 1024 + cu * 32 + w * 8;
        ST2_DEV(pd, pk);
      }
      DRAIN_VM();
      __syncthreads();
      if (tid == 0) ST_DW_DEV(myflag, (unsigned)(t + 1));
    }
    outb[(size_t)t * (BATCH * HID)] = hval;
  }
  float* hx = out + (size_t)T_STEPS * BATCH * HID;
  hx[(size_t)bglob * HID + u] = hval;
  float* cx = hx + BATCH * HID;
  cx[(size_t)bglob * HID + u] = c;
}

extern "C" void kernel_launch(void* const* d_in, const int* in_sizes, int n_in,
                              void* d_out, int out_size, void* d_ws, size_t ws_size,
                              hipStream_t stream) {
  const float* X  = (const float*)d_in[0];
  const float* Wf = (const float*)d_in[1];
  const float* bf = (const float*)d_in[2];
  const float* Wi = (const float*)d_in[3];
  const float* bi = (const float*)d_in[4];
  const float* Wg = (const float*)d_in[5];
  const float* bg = (const float*)d_in[6];
  const float* Wo = (const float*)d_in[7];
  const float* bo = (const float*)d_in[8];
  float* out = (float*)d_out;
  char* ws = (char*)d_ws;

  if (ws_size >= WS_NEED) {
    unsigned int*   flags = (unsigned int*)(ws + FLAGS_OFF);
    unsigned int*   xcdb  = (unsigned int*)(ws + XCDB_OFF);
    unsigned int*   xcnt  = (unsigned int*)(ws + XCNT_OFF);
    unsigned short* wpk   = (unsigned short*)(ws + WPK_OFF);
    unsigned short* xpk   = (unsigned short*)(ws + XPK_OFF);
    unsigned short* hbuf  = (unsigned short*)(ws + HBUF_OFF);
    hipMemsetAsync(ws, 0, WPK_OFF, stream);   // flags + detection scratch
    pack_w<<<768, 256, 0, stream>>>(Wf, Wi, Wg, Wo, wpk);
    pack_x<<<4096, 256, 0, stream>>>(X, xpk);
    lstm_mono<<<256, 256, 0, stream>>>(bf, bi, bg, bo, wpk, xpk, out,
                                       flags, xcdb, xcnt, hbuf);
  } else {
    unsigned int*   flags = (unsigned int*)(ws + FLAGS5_OFF);
    unsigned short* hbuf  = (unsigned short*)(ws + HBUF5_OFF);
    unsigned short* wpk   = (unsigned short*)(ws + WPK5_OFF);
    unsigned short* xpk   = (unsigned short*)(ws + XPK5_OFF);
    hipMemsetAsync(ws, 0, WPK5_OFF, stream);
    pack_w<<<768, 256, 0, stream>>>(Wf, Wi, Wg, Wo, wpk);
    pack_x<<<4096, 256, 0, stream>>>(X, xpk);
    lstm_rec_r5<<<256, 256, 0, stream>>>(bf, bi, bg, bo, wpk, xpk, out, flags, hbuf);
  }
}

// Round 11
// 1465.977 us; speedup vs baseline: 2.3106x; 1.1126x over previous
//
#include <hip/hip_runtime.h>
#include <stdint.h>

// Problem dims
#define T_STEPS 512
#define BATCH   64
#define DIN     256
#define HID     512
#define KTOT    768   // DIN + HID
#define NTEAMS  4
#define TB      16
#define KK_X    8     // k-tiles (K=32) covering x part
#define KK_H    16    // k-tiles covering h part
#define KK_ALL  24

// bounded spin: convert any protocol failure into a terminating wrong answer
#define POLL_BOUND (1 << 18)

typedef __bf16 v8bf __attribute__((ext_vector_type(8)));
typedef float  v4f  __attribute__((ext_vector_type(4)));
typedef unsigned int v4u __attribute__((ext_vector_type(4)));
typedef unsigned int v2u __attribute__((ext_vector_type(2)));

// ---------------- workspace layout ----------------
#define FLAGS_OFF 0                        // [4 team][32 cu] u32 @ 64B stride = 8192
#define WPK_OFF   16384                    // 3145728
#define XPK_OFF   (WPK_OFF + 3145728)      // 16777216
#define HB32_OFF  (XPK_OFF + 16777216)     // ring64 u32 slabs: 64*4*16*512*4 = 8388608
#define WS_NEED   ((size_t)HB32_OFF + 8388608u)
// R5 fallback layout (proven):
#define FLAGS5_OFF 0
#define HBUF5_OFF  8192                    // [4 team][2 parity][16][512] u16
#define WPK5_OFF   (HBUF5_OFF + 131072)
#define XPK5_OFF   (WPK5_OFF + 3145728)

// ---- single-instruction asm memory helpers (device scope = sc1 / IC point) ----
#define LOADX4_DEV(d, a, IMM) \
  asm volatile("global_load_dwordx4 %0, %1, off offset:" IMM " sc1" \
               : "=v"(d) : "v"(a) : "memory")
#define ST4_DEV(a, v) \
  asm volatile("global_store_dwordx4 %0, %1, off sc1" :: "v"(a), "v"(v) : "memory")
#define ST2_DEV(a, v) \
  asm volatile("global_store_dwordx2 %0, %1, off sc1" :: "v"(a), "v"(v) : "memory")
#define ST_DW_DEV(a, v) \
  asm volatile("global_store_dword %0, %1, off sc1" :: "v"(a), "v"(v) : "memory")
#define LOADX4(d, a) \
  asm volatile("global_load_dwordx4 %0, %1, off" : "=v"(d) : "v"(a) : "memory")
#define DRAIN_VM() asm volatile("s_waitcnt vmcnt(0)" ::: "memory")

static __device__ __forceinline__ unsigned int ld_flag_dev(const unsigned int* p) {
  unsigned int v;
  asm volatile("global_load_dword %0, %1, off sc1\n\ts_waitcnt vmcnt(0)"
               : "=v"(v) : "v"(p) : "memory");
  return v;
}

static __device__ __forceinline__ unsigned short f2bf(float x) {
  union { float f; uint32_t u; } v; v.f = x;
  uint32_t r = (v.u + 0x7fffu + ((v.u >> 16) & 1u)) >> 16;
  return (unsigned short)r;
}
static __device__ __forceinline__ float sigm(float x) {
  float e = __builtin_amdgcn_exp2f(-1.44269504f * x);
  return __builtin_amdgcn_rcpf(1.0f + e);
}
static __device__ __forceinline__ float tanh_(float x) {
  float e = __builtin_amdgcn_exp2f(2.88539008f * x);
  return 1.0f - 2.0f * __builtin_amdgcn_rcpf(e + 1.0f);
}

// ---- Prologue: pack weights into MFMA A-fragment order (bf16) ---- (proven)
__global__ void pack_w(const float* __restrict__ Wf, const float* __restrict__ Wi,
                       const float* __restrict__ Wg, const float* __restrict__ Wo,
                       unsigned short* __restrict__ wpk) {
  int n = blockIdx.x * 256 + threadIdx.x;
  int l  = n & 63;
  int kk = (n >> 6) % KK_ALL;
  int wv = (n >> 6) / KK_ALL;
  int row  = l & 15;
  int gate = row & 3;
  int unit = (wv >> 2) * 16 + (wv & 3) * 4 + (row >> 2);
  int col  = kk * 32 + (l >> 4) * 8;
  const float* W = (gate == 0) ? Wf : (gate == 1) ? Wi : (gate == 2) ? Wg : Wo;
  const float* src = W + (size_t)unit * KTOT + col;
  unsigned short* dst = wpk + (size_t)n * 8;
#pragma unroll
  for (int e = 0; e < 8; e++) dst[e] = f2bf(src[e]);
}

// ---- Prologue: pack x into MFMA B-fragment order (bf16) ---- (proven)
__global__ void pack_x(const float* __restrict__ X, unsigned short* __restrict__ xpk) {
  int n = blockIdx.x * 256 + threadIdx.x;
  int l    = n & 63;
  int kk   = (n >> 6) & 7;
  int team = (n >> 9) & 3;
  int t    = n >> 11;
  int b    = team * TB + (l & 15);
  int col  = kk * 32 + (l >> 4) * 8;
  const float* src = X + ((size_t)(t * BATCH + b)) * DIN + col;
  unsigned short* dst = xpk + (size_t)n * 8;
#pragma unroll
  for (int e = 0; e < 8; e++) dst[e] = f2bf(src[e]);
}

// =====================================================================
// SPEC kernel: R5 protocol + speculative staging. h published as u32
// (bf16<<16 | step_tag) into a 64-deep monotonic ring. Consumers issue
// the stage load optimistically, verify tags in-register; on miss fall
// back to the R5 sc1 flag poll + re-load. Tear-proof (per-u32 tags),
// cold-proof (ring memset, tags>=1), replay-proof (value determinism).
// =====================================================================
__global__ void __launch_bounds__(256, 1)
lstm_spec(const float* __restrict__ bf_, const float* __restrict__ bi_,
          const float* __restrict__ bg_, const float* __restrict__ bo_,
          const unsigned short* __restrict__ wpk, const unsigned short* __restrict__ xpk,
          float* __restrict__ out, unsigned int* flags, unsigned int* hb32) {
  int blk  = blockIdx.x;
  int team = blk & 7;
  if (team >= NTEAMS) return;
  int cu  = blk >> 3;              // 0..31
  int tid = threadIdx.x;
  int w   = tid >> 6, l = tid & 63;
  int brow = l & 15;
  int ul   = l >> 4;
  int u    = cu * 16 + w * 4 + ul;
  int bglob = team * TB + brow;

  __shared__ v4u hls[2048];        // 2 x 16 KB swizzled bf16 image (double buffer)

  // stationary weight fragments (forced resident via asm loads; proven)
  v4u wfu[KK_ALL];
  {
    const char* wp = (const char*)(wpk + ((size_t)(cu * 4 + w)) * (KK_ALL * 512) + l * 8);
#pragma unroll
    for (int kk = 0; kk < KK_ALL; kk++) LOADX4(wfu[kk], wp + (size_t)kk * 1024);
    DRAIN_VM();
  }
  float b0 = bf_[u], b1 = bi_[u], b2 = bg_[u], b3 = bo_[u];
  float c = 0.0f, hval = 0.0f;

  unsigned int* ftm = flags + (size_t)team * 32 * 16;  // 32 flags, 64B stride
  unsigned int* myflag = ftm + (size_t)cu * 16;

  // consumer mapping: row r = w*4+(l>>4); 16 lanes cover the 2KB u32 row
  int r    = w * 4 + (l >> 4);
  int scol = l & 15;

  float* outb = out + (size_t)bglob * HID + u;
  const unsigned int SEL = 0x07060302u;   // R7-verified hi16 extraction pair

  for (int t = 0; t < T_STEPS; t++) {
    // ring slab for step t (consumed) and t+1 (published)
    char* slab_t = (char*)(hb32 + ((size_t)(t & 63) * NTEAMS + team) * (TB * HID));
    char* slab_n = (char*)(hb32 + ((size_t)((t + 1) & 63) * NTEAMS + team) * (TB * HID));

    v4u p0, p1, p2, p3, p4, p5, p6, p7;
    const char* sb = slab_t + r * 2048 + scol * 32;
    if (t > 0) {
      // 1) optimistic stage issue (sc1), sampled ~1 RT from now
      LOADX4_DEV(p0, sb, "0");    LOADX4_DEV(p1, sb, "16");
      LOADX4_DEV(p2, sb, "512");  LOADX4_DEV(p3, sb, "528");
      LOADX4_DEV(p4, sb, "1024"); LOADX4_DEV(p5, sb, "1040");
      LOADX4_DEV(p6, sb, "1536"); LOADX4_DEV(p7, sb, "1552");
    }

    // 2) x-part B-frags + x-MFMAs under the stage latency
    v8bf xf[KK_X];
    {
      const v8bf* xp = (const v8bf*)(xpk + ((size_t)(t * NTEAMS + team)) * (KK_X * 512) + l * 8);
#pragma unroll
      for (int kk = 0; kk < KK_X; kk++) xf[kk] = xp[kk * 64];
    }
    v4f acc[4];
    acc[0] = (v4f){b0, b1, b2, b3};
    acc[1] = (v4f){0.f, 0.f, 0.f, 0.f};
    acc[2] = (v4f){0.f, 0.f, 0.f, 0.f};
    acc[3] = (v4f){0.f, 0.f, 0.f, 0.f};
#pragma unroll
    for (int kk = 0; kk < KK_X; kk++)
      acc[kk & 3] = __builtin_amdgcn_mfma_f32_16x16x32_bf16(
          __builtin_bit_cast(v8bf, wfu[kk]), xf[kk], acc[kk & 3], 0, 0, 0);

    if (t > 0) {
      DRAIN_VM();
      __builtin_amdgcn_sched_barrier(0);   // rule #18: check reads asm outputs

      // 3) tag check: every u32's low16 must equal t
      unsigned int tg = (unsigned)t;
      unsigned int m;
      m  = ((p0.x ^ tg) | (p0.y ^ tg) | (p0.z ^ tg) | (p0.w ^ tg));
      m |= ((p1.x ^ tg) | (p1.y ^ tg) | (p1.z ^ tg) | (p1.w ^ tg));
      m |= ((p2.x ^ tg) | (p2.y ^ tg) | (p2.z ^ tg) | (p2.w ^ tg));
      m |= ((p3.x ^ tg) | (p3.y ^ tg) | (p3.z ^ tg) | (p3.w ^ tg));
      m |= ((p4.x ^ tg) | (p4.y ^ tg) | (p4.z ^ tg) | (p4.w ^ tg));
      m |= ((p5.x ^ tg) | (p5.y ^ tg) | (p5.z ^ tg) | (p5.w ^ tg));
      m |= ((p6.x ^ tg) | (p6.y ^ tg) | (p6.z ^ tg) | (p6.w ^ tg));
      m |= ((p7.x ^ tg) | (p7.y ^ tg) | (p7.z ^ tg) | (p7.w ^ tg));
      m &= 0xFFFFu;
      bool hit = __all(m == 0);

      if (!hit) {
        // 4) fallback: R5 flag poll (sc1, 32 flags, bounded), then re-stage
        const unsigned int* pp = ftm + (size_t)(l & 31) * 16;
        int guard = 0;
        while (true) {
          unsigned int v = ld_flag_dev(pp);
          if (__all(v >= tg)) break;
          if (++guard > POLL_BOUND) break;   // degrade, never hang
        }
        LOADX4_DEV(p0, sb, "0");    LOADX4_DEV(p1, sb, "16");
        LOADX4_DEV(p2, sb, "512");  LOADX4_DEV(p3, sb, "528");
        LOADX4_DEV(p4, sb, "1024"); LOADX4_DEV(p5, sb, "1040");
        LOADX4_DEV(p6, sb, "1536"); LOADX4_DEV(p7, sb, "1552");
        DRAIN_VM();
        __builtin_amdgcn_sched_barrier(0);
      }

      // 5) unpack hi16 -> bf16 image rows (R5-identical LDS layout + swizzle)
      char* hl = (char*)hls + (t & 1) * 16384;
      int ob = r * 1024 + scol * 16;
      int sz = (r & 7) << 4;
      v4u o;
      o.x = __builtin_amdgcn_perm(p0.y, p0.x, SEL);
      o.y = __builtin_amdgcn_perm(p0.w, p0.z, SEL);
      o.z = __builtin_amdgcn_perm(p1.y, p1.x, SEL);
      o.w = __builtin_amdgcn_perm(p1.w, p1.z, SEL);
      *(v4u*)(hl + ((ob + 0) ^ sz)) = o;
      o.x = __builtin_amdgcn_perm(p2.y, p2.x, SEL);
      o.y = __builtin_amdgcn_perm(p2.w, p2.z, SEL);
      o.z = __builtin_amdgcn_perm(p3.y, p3.x, SEL);
      o.w = __builtin_amdgcn_perm(p3.w, p3.z, SEL);
      *(v4u*)(hl + ((ob + 256) ^ sz)) = o;
      o.x = __builtin_amdgcn_perm(p4.y, p4.x, SEL);
      o.y = __builtin_amdgcn_perm(p4.w, p4.z, SEL);
      o.z = __builtin_amdgcn_perm(p5.y, p5.x, SEL);
      o.w = __builtin_amdgcn_perm(p5.w, p5.z, SEL);
      *(v4u*)(hl + ((ob + 512) ^ sz)) = o;
      o.x = __builtin_amdgcn_perm(p6.y, p6.x, SEL);
      o.y = __builtin_amdgcn_perm(p6.w, p6.z, SEL);
      o.z = __builtin_amdgcn_perm(p7.y, p7.x, SEL);
      o.w = __builtin_amdgcn_perm(p7.w, p7.z, SEL);
      *(v4u*)(hl + ((ob + 768) ^ sz)) = o;
      __syncthreads();   // barrier B: writes -> reads (dbuf covers cross-step)

      // 6) h-part MFMAs from LDS (R5-proven swizzled layout)
#pragma unroll
      for (int kk = 0; kk < KK_H; kk++) {
        int off = (brow * 1024 + kk * 64 + ul * 16) ^ ((brow & 7) << 4);
        v8bf hf = *(const v8bf*)(hl + off);
        acc[kk & 3] = __builtin_amdgcn_mfma_f32_16x16x32_bf16(
            __builtin_bit_cast(v8bf, wfu[KK_X + kk]), hf, acc[kk & 3], 0, 0, 0);
      }
    }

    v4f g4 = (acc[0] + acc[1]) + (acc[2] + acc[3]);
    float fg = sigm(g4[0]);
    float ig = sigm(g4[1]);
    float gg = tanh_(g4[2]);
    float og = sigm(g4[3]);
    c    = fg * c + ig * gg;
    hval = og * tanh_(c);

    if (t < T_STEPS - 1) {
      // publish h_{t+1}: ONE tagged dwordx4 per lane<16
      float h0 = __shfl(hval, brow);
      float h1 = __shfl(hval, brow + 16);
      float h2 = __shfl(hval, brow + 32);
      float h3 = __shfl(hval, brow + 48);
      if (l < 16) {
        unsigned int tg1 = (unsigned)(t + 1);
        v4u pk;
        pk.x = ((unsigned)f2bf(h0) << 16) | tg1;
        pk.y = ((unsigned)f2bf(h1) << 16) | tg1;
        pk.z = ((unsigned)f2bf(h2) << 16) | tg1;
        pk.w = ((unsigned)f2bf(h3) << 16) | tg1;
        char* pd = slab_n + brow * 2048 + cu * 64 + w * 16;
        ST4_DEV(pd, pk);
      }
      DRAIN_VM();          // publish acked at IC
      __syncthreads();     // barrier A: all 4 waves drained
      if (tid == 0) ST_DW_DEV(myflag, (unsigned)(t + 1));
    }
    // out store off the critical path
    outb[(size_t)t * (BATCH * HID)] = hval;
  }

  // final hx, cx
  float* hx = out + (size_t)T_STEPS * BATCH * HID;
  hx[(size_t)bglob * HID + u] = hval;
  float* cx = hx + BATCH * HID;
  cx[(size_t)bglob * HID + u] = c;
}

// =====================================================================
// R5 kernel, verbatim (proven 1348us) — fallback when ws too small
// =====================================================================
__global__ void __launch_bounds__(256, 1)
lstm_rec_r5(const float* __restrict__ bf_, const float* __restrict__ bi_,
            const float* __restrict__ bg_, const float* __restrict__ bo_,
            const unsigned short* __restrict__ wpk, const unsigned short* __restrict__ xpk,
            float* __restrict__ out, unsigned int* flags, unsigned short* hbuf) {
  int blk  = blockIdx.x;
  int team = blk & 7;
  if (team >= NTEAMS) return;
  int cu  = blk >> 3;
  int tid = threadIdx.x;
  int w   = tid >> 6, l = tid & 63;
  int brow = l & 15;
  int ul   = l >> 4;
  int u    = cu * 16 + w * 4 + ul;
  int bglob = team * TB + brow;

  __shared__ v4u hls[1024];
  char* hl = (char*)hls;

  v4u wfu[KK_ALL];
  {
    const char* wp = (const char*)(wpk + ((size_t)(cu * 4 + w)) * (KK_ALL * 512) + l * 8);
#pragma unroll
    for (int kk = 0; kk < KK_ALL; kk++) LOADX4(wfu[kk], wp + (size_t)kk * 1024);
    DRAIN_VM();
  }
  float b0 = bf_[u], b1 = bi_[u], b2 = bg_[u], b3 = bo_[u];
  float c = 0.0f, hval = 0.0f;

  char* slab0 = (char*)(hbuf + (size_t)team * 2 * (TB * HID));
  char* slab1 = slab0 + TB * HID * 2;
  unsigned int* ftm = flags + (size_t)team * 32 * 16;
  unsigned int* myflag = ftm + (size_t)cu * 16;
  float* outb = out + (size_t)bglob * HID + u;

  for (int t = 0; t < T_STEPS; t++) {
    v8bf xf[KK_X];
    {
      const v8bf* xp = (const v8bf*)(xpk + ((size_t)(t * NTEAMS + team)) * (KK_X * 512) + l * 8);
#pragma unroll
      for (int kk = 0; kk < KK_X; kk++) xf[kk] = xp[kk * 64];
    }
    if (t > 0) {
      if (w == 0) {
        const unsigned int* pp = ftm + (size_t)(l & 31) * 16;
        int guard = 0;
        while (true) {
          unsigned int v = ld_flag_dev(pp);
          if (__all(v >= (unsigned)t)) break;
          if (++guard > POLL_BOUND) break;
        }
      }
      __syncthreads();
    }
    v4u s0, s1, s2, s3;
    {
      const char* sb = ((t & 1) ? slab1 : slab0) + w * 4096 + l * 16;
      LOADX4_DEV(s0, sb, "0");
      LOADX4_DEV(s1, sb, "1024");
      LOADX4_DEV(s2, sb, "2048");
      LOADX4_DEV(s3, sb, "3072");
    }
    v4f acc[4];
    acc[0] = (v4f){b0, b1, b2, b3};
    acc[1] = (v4f){0.f, 0.f, 0.f, 0.f};
    acc[2] = (v4f){0.f, 0.f, 0.f, 0.f};
    acc[3] = (v4f){0.f, 0.f, 0.f, 0.f};
#pragma unroll
    for (int kk = 0; kk < KK_X; kk++)
      acc[kk & 3] = __builtin_amdgcn_mfma_f32_16x16x32_bf16(
          __builtin_bit_cast(v8bf, wfu[kk]), xf[kk], acc[kk & 3], 0, 0, 0);
    DRAIN_VM();
    __builtin_amdgcn_sched_barrier(0);
    {
      int r = w * 4;
      *(v4u*)(hl + (((r + 0) * 1024 + l * 16) ^ (((r + 0) & 7) << 4))) = s0;
      *(v4u*)(hl + (((r + 1) * 1024 + l * 16) ^ (((r + 1) & 7) << 4))) = s1;
      *(v4u*)(hl + (((r + 2) * 1024 + l * 16) ^ (((r + 2) & 7) << 4))) = s2;
      *(v4u*)(hl + (((r + 3) * 1024 + l * 16) ^ (((r + 3) & 7) << 4))) = s3;
    }
    __syncthreads();
#pragma unroll
    for (int kk = 0; kk < KK_H; kk++) {
      int off = (brow * 1024 + kk * 64 + ul * 16) ^ ((brow & 7) << 4);
      v8bf hf = *(const v8bf*)(hl + off);
      acc[kk & 3] = __builtin_amdgcn_mfma_f32_16x16x32_bf16(
          __builtin_bit_cast(v8bf, wfu[KK_X + kk]), hf, acc[kk & 3], 0, 0, 0);
    }
    v4f g4 = (acc[0] + acc[1]) + (acc[2] + acc[3]);
    float fg = sigm(g4[0]);
    float ig = sigm(g4[1]);
    float gg = tanh_(g4[2]);
    float og = sigm(g4[3]);
    c    = fg * c + ig * gg;
    hval = og * tanh_(c);
    if (t < T_STEPS - 1) {
      float h0 = __shfl(hval, brow);
      float h1 = __shfl(hval, brow + 16);
      float h2 = __shfl(hval, brow + 32);
      float h3 = __shfl(hval, brow + 48);
      if (l < 16) {
        v2u pk;
        pk.x = (unsigned)f2bf(h0) | ((unsigned)f2bf(h1) << 16);
        pk.y = (unsigned)f2bf(h2) | ((unsigned)f2bf(h3) << 16);
        char* pd = (((t + 1) & 1) ? slab1 : slab0) + brow * 1024 + cu * 32 + w * 8;
        ST2_DEV(pd, pk);
      }
      DRAIN_VM();
      __syncthreads();
      if (tid == 0) ST_DW_DEV(myflag, (unsigned)(t + 1));
    }
    outb[(size_t)t * (BATCH * HID)] = hval;
  }
  float* hx = out + (size_t)T_STEPS * BATCH * HID;
  hx[(size_t)bglob * HID + u] = hval;
  float* cx = hx + BATCH * HID;
  cx[(size_t)bglob * HID + u] = c;
}

extern "C" void kernel_launch(void* const* d_in, const int* in_sizes, int n_in,
                              void* d_out, int out_size, void* d_ws, size_t ws_size,
                              hipStream_t stream) {
  const float* X  = (const float*)d_in[0];
  const float* Wf = (const float*)d_in[1];
  const float* bf = (const float*)d_in[2];
  const float* Wi = (const float*)d_in[3];
  const float* bi = (const float*)d_in[4];
  const float* Wg = (const float*)d_in[5];
  const float* bg = (const float*)d_in[6];
  const float* Wo = (const float*)d_in[7];
  const float* bo = (const float*)d_in[8];
  float* out = (float*)d_out;
  char* ws = (char*)d_ws;

  if (ws_size >= WS_NEED) {
    unsigned int*   flags = (unsigned int*)(ws + FLAGS_OFF);
    unsigned short* wpk   = (unsigned short*)(ws + WPK_OFF);
    unsigned short* xpk   = (unsigned short*)(ws + XPK_OFF);
    unsigned int*   hb32  = (unsigned int*)(ws + HB32_OFF);
    hipMemsetAsync(ws, 0, WPK_OFF, stream);           // flags
    hipMemsetAsync(ws + HB32_OFF, 0, 8388608, stream); // ring tags (cold safety)
    pack_w<<<768, 256, 0, stream>>>(Wf, Wi, Wg, Wo, wpk);
    pack_x<<<4096, 256, 0, stream>>>(X, xpk);
    lstm_spec<<<256, 256, 0, stream>>>(bf, bi, bg, bo, wpk, xpk, out, flags, hb32);
  } else {
    unsigned int*   flags = (unsigned int*)(ws + FLAGS5_OFF);
    unsigned short* hbuf  = (unsigned short*)(ws + HBUF5_OFF);
    unsigned short* wpk   = (unsigned short*)(ws + WPK5_OFF);
    unsigned short* xpk   = (unsigned short*)(ws + XPK5_OFF);
    hipMemsetAsync(ws, 0, WPK5_OFF, stream);
    pack_w<<<768, 256, 0, stream>>>(Wf, Wi, Wg, Wo, wpk);
    pack_x<<<4096, 256, 0, stream>>>(X, xpk);
    lstm_rec_r5<<<256, 256, 0, stream>>>(bf, bi, bg, bo, wpk, xpk, out, flags, hbuf);
  }
}